// Round 7
// baseline (609.866 us; speedup 1.0000x reference)
//
#include <hip/hip_runtime.h>
#include <math.h>

#define NN   50000
#define EE   800000
#define MM   3
#define KDIM 256      // IN_DIM
#define FF   256      // H*D
#define HH   8
#define DD   32
#define HID  128
#define SLOPE 0.2f
#define BK   32       // k-slice per MFMA stage
#define CAP  80       // fixed CSR capacity per node (Poisson(16): P(deg>=80)~1e-30)

typedef unsigned short u16;
typedef unsigned int   u32;
typedef __attribute__((ext_vector_type(8))) short short8;   // 8 bf16 = 4 VGPRs
typedef __attribute__((ext_vector_type(4))) float floatx4;  // MFMA acc

__device__ __forceinline__ float eluf(float x) { return x > 0.f ? x : expm1f(x); }

__device__ __forceinline__ float b2f_lo(u32 u) {
    union { u32 i; float f; } v; v.i = u << 16; return v.f;
}
__device__ __forceinline__ float b2f_hi(u32 u) {
    union { u32 i; float f; } v; v.i = u & 0xffff0000u; return v.f;
}
__device__ __forceinline__ u16 f2b(float f) {
    union { float f; u32 i; } v; v.f = f;
    u32 lsb = (v.i >> 16) & 1u;
    v.i += 0x7fffu + lsb;
    return (u16)(v.i >> 16);
}
__device__ __forceinline__ u32 pack2(float lo, float hi) {
    return (u32)f2b(lo) | ((u32)f2b(hi) << 16);
}

// async global->LDS, 16B per lane; LDS dest = wave-uniform base + lane*16
__device__ __forceinline__ void gload_lds16(const u16* g, u16* l) {
    __builtin_amdgcn_global_load_lds(
        (const __attribute__((address_space(1))) unsigned int*)(const void*)g,
        (__attribute__((address_space(3))) unsigned int*)(void*)l,
        16, 0, 0);
}

// ---------------------------------------------------------------------------
// k_prep_w: cast_w + cast_w1 merged (small weights only).
// ---------------------------------------------------------------------------
__global__ __launch_bounds__(256) void k_prep_w(
    const float* __restrict__ fcw,  u16* __restrict__ fcwt,
    const float* __restrict__ w1,   u16* __restrict__ w1t)
{
    const int bid = blockIdx.x;
    if (bid < 768) {
        int k = bid & 255, me = bid >> 8, n = threadIdx.x;
        float v = fcw[((size_t)me * KDIM + k) * FF + n];
        fcwt[((size_t)me * FF + n) * KDIM + k] = f2b(v);
    } else {
        int idx = (bid - 768) * 256 + threadIdx.x;   // 32768 elems
        int k = idx >> 7, n = idx & 127;
        w1t[(size_t)n * KDIM + k] = f2b(w1[(size_t)k * HID + n]);
    }
}

// ---------------------------------------------------------------------------
// feat[m] = h @ fcw[m] via MFMA bf16 + fused edge scatter prologue.
// R6: cy is now a launch param (2 dispatches of grid (391, MM)) so feat's
// dur drops below sem/combine for top-5 attribution.  Edge pool split uses
// the same flattened-bid formula -> identical coverage.
// ---------------------------------------------------------------------------
__global__ __launch_bounds__(256) void k_feat_all(
    const float* __restrict__ hmat,    // [N,256] f32
    const u16*   __restrict__ fcwt,    // [M][256(n)][256(k)] bf16
    const float* __restrict__ al,      // [M,H,D]
    const float* __restrict__ ar,      // [M,H,D]
    u16*   __restrict__ featb,         // [M,N,256] bf16
    float* __restrict__ el,            // [M,N,H]
    float* __restrict__ er,            // [M,N,H]
    const int* __restrict__ src,       // [M*E]
    const int* __restrict__ dst,       // [M*E]
    int* __restrict__ cnt,             // [M,NN]
    u16* __restrict__ srt,             // [M,CAP,NN] slot-major
    int cy)                            // column half: heads cy*4..cy*4+3
{
    __shared__ u16 As[128 * BK];   // 8 KB, linear+swizzled
    __shared__ u16 Bs[128 * BK];   // 8 KB

    const int t = threadIdx.x;
    const int m = blockIdx.y;

    // --- fused scatter: 4 consecutive edges per thread (EE%4==0) ---
    {
        int bid = blockIdx.x + 391 * (cy + 2 * m);
        long long base = ((long long)bid * 256 + t) * 4;
        if (base < (long long)MM * EE) {
            int4 d4 = *(const int4*)(dst + base);
            int4 s4 = *(const int4*)(src + base);
            int me = (int)(base / EE);
            int* cnt_m = cnt + (size_t)me * NN;
            u16* srt_m = srt + (size_t)me * CAP * NN;
            int dd4[4] = { d4.x, d4.y, d4.z, d4.w };
            int ss4[4] = { s4.x, s4.y, s4.z, s4.w };
            #pragma unroll
            for (int j = 0; j < 4; ++j) {
                int slot = atomicAdd(&cnt_m[dd4[j]], 1);
                if (slot < CAP) srt_m[(size_t)slot * NN + dd4[j]] = (u16)ss4[j];
            }
        }
    }

    const int n0 = blockIdx.x * 128;
    const int c_base = cy * 128;
    const int wave = t >> 6, lane = t & 63;
    const int wr = wave >> 1, wc = wave & 1;
    const int quad = lane >> 4, l15 = lane & 15;

    const u16* fcwt_m = fcwt + (size_t)m * FF * KDIM;
    const float* al_m = al + (size_t)m * HH * DD;
    const float* ar_m = ar + (size_t)m * HH * DD;

    const float* pAf[2]; const u16* pB[2]; u16* lA[2]; u16* lB[2];
    #pragma unroll
    for (int i = 0; i < 2; ++i) {
        int r  = wave * 32 + i * 16 + (lane >> 2);
        int cs = (((lane & 3) ^ (r & 3)) << 3);
        pAf[i] = hmat + (size_t)min(n0 + r, NN - 1) * KDIM + cs;  // f32 source
        pB[i]  = fcwt_m + (size_t)(c_base + r) * KDIM + cs;
        lA[i] = (u16*)As + (wave * 2 + i) * 512 + lane * 8;       // per-lane 16B
        lB[i] = (u16*)Bs + (wave * 2 + i) * 512;                  // wave-uniform
    }

    int aoff[4], boff[4];
    #pragma unroll
    for (int ti = 0; ti < 4; ++ti) {
        int rowa = wr * 64 + ti * 16 + l15;
        aoff[ti] = rowa * BK + (((quad ^ (rowa & 3))) << 3);
        int rowb = wc * 64 + ti * 16 + l15;
        boff[ti] = rowb * BK + (((quad ^ (rowb & 3))) << 3);
    }

    floatx4 acc[4][4] = {};

    for (int k0 = 0; k0 < KDIM; k0 += BK) {
        __syncthreads();
        #pragma unroll
        for (int i = 0; i < 2; ++i)
            gload_lds16(pB[i] + k0, lB[i]);
        #pragma unroll
        for (int i = 0; i < 2; ++i) {
            float4 v0 = *(const float4*)(pAf[i] + k0);
            float4 v1 = *(const float4*)(pAf[i] + k0 + 4);
            uint4 u;
            u.x = pack2(v0.x, v0.y); u.y = pack2(v0.z, v0.w);
            u.z = pack2(v1.x, v1.y); u.w = pack2(v1.z, v1.w);
            *(uint4*)(lA[i]) = u;
        }
        __syncthreads();

        short8 afr[4], bfr[4];
        #pragma unroll
        for (int ti = 0; ti < 4; ++ti)
            afr[ti] = *(const short8*)(&As[aoff[ti]]);
        #pragma unroll
        for (int tj = 0; tj < 4; ++tj)
            bfr[tj] = *(const short8*)(&Bs[boff[tj]]);
        #pragma unroll
        for (int ti = 0; ti < 4; ++ti)
            #pragma unroll
            for (int tj = 0; tj < 4; ++tj)
                acc[ti][tj] = __builtin_amdgcn_mfma_f32_16x16x32_bf16(
                    afr[ti], bfr[tj], acc[ti][tj], 0, 0, 0);
    }

    float alv[4], arv[4];
    #pragma unroll
    for (int tj = 0; tj < 4; ++tj) {
        int h = cy * 4 + wc * 2 + (tj >> 1);
        int dcol = (tj & 1) * 16 + l15;
        alv[tj] = al_m[h * DD + dcol];
        arv[tj] = ar_m[h * DD + dcol];
    }
    const int h0 = cy * 4 + wc * 2, h1 = h0 + 1;

    #pragma unroll
    for (int ti = 0; ti < 4; ++ti) {
        #pragma unroll
        for (int reg = 0; reg < 4; ++reg) {
            int n = n0 + wr * 64 + ti * 16 + quad * 4 + reg;
            bool ok = n < NN;
            if (ok) {
                #pragma unroll
                for (int tj = 0; tj < 4; ++tj) {
                    int c = c_base + wc * 64 + tj * 16 + l15;
                    featb[((size_t)m * NN + n) * FF + c] = f2b(acc[ti][tj][reg]);
                }
            }
            float pl0 = acc[ti][0][reg] * alv[0] + acc[ti][1][reg] * alv[1];
            float pl1 = acc[ti][2][reg] * alv[2] + acc[ti][3][reg] * alv[3];
            float pr0 = acc[ti][0][reg] * arv[0] + acc[ti][1][reg] * arv[1];
            float pr1 = acc[ti][2][reg] * arv[2] + acc[ti][3][reg] * arv[3];
            #pragma unroll
            for (int s = 1; s < 16; s <<= 1) {
                pl0 += __shfl_xor(pl0, s); pl1 += __shfl_xor(pl1, s);
                pr0 += __shfl_xor(pr0, s); pr1 += __shfl_xor(pr1, s);
            }
            if (l15 == 0 && ok) {
                el[((size_t)m * NN + n) * HH + h0] = pl0;
                el[((size_t)m * NN + n) * HH + h1] = pl1;
                er[((size_t)m * NN + n) * HH + h0] = pr0;
                er[((size_t)m * NN + n) * HH + h1] = pr1;
            }
        }
    }
}

// ---------------------------------------------------------------------------
// Aggregation — R6: split into 3 d-range dispatches (same cross-m grid
// structure that measured best).  (sum of pieces - 189us) = bubble cost.
// ---------------------------------------------------------------------------
__global__ __launch_bounds__(256) void k_aggr_all(
    const int* __restrict__ cnt,        // [M,NN]
    const u16* __restrict__ srt,        // [M,CAP,NN] slot-major
    const float* __restrict__ el,       // [M,NN,8]
    const float* __restrict__ er,       // [M,NN,8]
    const u16* __restrict__ featb,      // [M,NN,256] bf16
    const float* __restrict__ bias,     // [M,256]
    u16* __restrict__ z,                // [M,NN,256] bf16
    int d_base)
{
    __shared__ float alpha_s[4][2][CAP][HH];  // 20.5 KB
    __shared__ int   srcoff[4][2][CAP];       // 2.56 KB (s*FF)

    const int m = blockIdx.y;
    const int wave = threadIdx.x >> 6, lane = threadIdx.x & 63;
    const int half = lane >> 5, L = lane & 31;
    const int d = d_base + blockIdx.x * 8 + wave * 2 + half;

    const int deg = min(cnt[(size_t)m * NN + d], CAP);
    const float* el_m = el + (size_t)m * NN * HH;
    const u16* feat_m = featb + (size_t)m * NN * FF;

    #pragma unroll
    for (int i = 0; i < 3; ++i) {
        int slot = L + i * 32;
        if (slot < deg)
            srcoff[wave][half][slot] =
                (int)srt[(size_t)(m * CAP + slot) * NN + d] * FF;
    }

    // phase A: exp + esum. lane = edge (L>>3) x head (L&7), unroll x2
    const int hA = L & 7;
    const float er_d = er[((size_t)m * NN + d) * HH + hA];
    float esum_r = 0.f;
    const int nIter = (deg + 3) >> 2;
    int i = 0;
    for (; i + 2 <= nIter; i += 2) {
        int j0 = i * 4 + (L >> 3);
        int j1 = j0 + 4;
        bool v0 = j0 < deg, v1 = j1 < deg;
        int so0 = v0 ? srcoff[wave][half][j0] : 0;
        int so1 = v1 ? srcoff[wave][half][j1] : 0;
        float x0 = el_m[(size_t)(so0 >> 5) + hA] + er_d;
        float x1 = el_m[(size_t)(so1 >> 5) + hA] + er_d;
        x0 = x0 >= 0.f ? x0 : SLOPE * x0;  x0 = fminf(x0, 60.f);
        x1 = x1 >= 0.f ? x1 : SLOPE * x1;  x1 = fminf(x1, 60.f);
        float e0 = v0 ? expf(x0) : 0.f;
        float e1 = v1 ? expf(x1) : 0.f;
        if (v0) alpha_s[wave][half][j0][hA] = e0;
        if (v1) alpha_s[wave][half][j1][hA] = e1;
        float g = e0 + e1;
        g += __shfl_xor(g, 8); g += __shfl_xor(g, 16);
        esum_r += g;
    }
    for (; i < nIter; ++i) {
        int j = i * 4 + (L >> 3);
        float e = 0.f;
        if (j < deg) {
            int so = srcoff[wave][half][j];
            float x = el_m[(size_t)(so >> 5) + hA] + er_d;
            x = x >= 0.f ? x : SLOPE * x;
            x = fminf(x, 60.f);
            e = expf(x);
            alpha_s[wave][half][j][hA] = e;
        }
        float g = e;
        g += __shfl_xor(g, 8); g += __shfl_xor(g, 16);
        esum_r += g;
    }
    float inv_r = 1.f / fmaxf(esum_r, 1e-38f);

    // phase B: lane covers channels L*8..L*8+7 of dst d; head = L>>2
    const float inv_g = __shfl(inv_r, (lane & 32) | (L >> 2));
    const int hB = L >> 2;
    const u16* frow = feat_m + L * 8;
    float acc[8] = {0.f, 0.f, 0.f, 0.f, 0.f, 0.f, 0.f, 0.f};

#define ACC8(f, a)                                                  \
    acc[0] += (a) * b2f_lo((f).x); acc[1] += (a) * b2f_hi((f).x);   \
    acc[2] += (a) * b2f_lo((f).y); acc[3] += (a) * b2f_hi((f).y);   \
    acc[4] += (a) * b2f_lo((f).z); acc[5] += (a) * b2f_hi((f).z);   \
    acc[6] += (a) * b2f_lo((f).w); acc[7] += (a) * b2f_hi((f).w);

    int j = 0;
    for (; j + 4 <= deg; j += 4) {
        int so0 = srcoff[wave][half][j + 0];
        int so1 = srcoff[wave][half][j + 1];
        int so2 = srcoff[wave][half][j + 2];
        int so3 = srcoff[wave][half][j + 3];
        float a0 = alpha_s[wave][half][j + 0][hB];
        float a1 = alpha_s[wave][half][j + 1][hB];
        float a2 = alpha_s[wave][half][j + 2][hB];
        float a3 = alpha_s[wave][half][j + 3][hB];
        uint4 f0 = *(const uint4*)(frow + so0);
        uint4 f1 = *(const uint4*)(frow + so1);
        uint4 f2 = *(const uint4*)(frow + so2);
        uint4 f3 = *(const uint4*)(frow + so3);
        ACC8(f0, a0); ACC8(f1, a1); ACC8(f2, a2); ACC8(f3, a3);
    }
    for (; j < deg; ++j) {
        int so = srcoff[wave][half][j];
        float a = alpha_s[wave][half][j][hB];
        uint4 f = *(const uint4*)(frow + so);
        ACC8(f, a);
    }
#undef ACC8

    #pragma unroll
    for (int k = 0; k < 8; ++k) acc[k] *= inv_g;

    const float4 b0 = *(const float4*)(bias + (size_t)m * FF + L * 8);
    const float4 b1 = *(const float4*)(bias + (size_t)m * FF + L * 8 + 4);
    uint4 o;
    o.x = pack2(eluf(acc[0] + b0.x), eluf(acc[1] + b0.y));
    o.y = pack2(eluf(acc[2] + b0.z), eluf(acc[3] + b0.w));
    o.z = pack2(eluf(acc[4] + b1.x), eluf(acc[5] + b1.y));
    o.w = pack2(eluf(acc[6] + b1.z), eluf(acc[7] + b1.w));
    *(uint4*)(z + ((size_t)m * NN + d) * FF + L * 8) = o;
}

// ---------------------------------------------------------------------------
// wsum[m] = sum_n tanh(z[m] @ w1 + b1) @ w2  via MFMA (single dispatch).
// ---------------------------------------------------------------------------
__global__ __launch_bounds__(256) void k_sem_all(
    const u16* __restrict__ z,        // [M,NN,256] bf16
    const u16* __restrict__ w1t,      // [128(n)][256(k)] bf16
    const float* __restrict__ b1,     // [128]
    const float* __restrict__ w2,     // [128]
    float* __restrict__ wsum)         // [M]
{
    __shared__ u16 As[128 * BK];
    __shared__ u16 Bs[128 * BK];

    const int n0 = blockIdx.x * 128;
    const int m  = blockIdx.y;
    const int t = threadIdx.x;
    const int wave = t >> 6, lane = t & 63;
    const int wr = wave >> 1, wc = wave & 1;
    const int quad = lane >> 4, l15 = lane & 15;

    const u16* z_m = z + (size_t)m * NN * FF;

    const u16* pA[2]; const u16* pB[2]; u16* lA[2]; u16* lB[2];
    #pragma unroll
    for (int i = 0; i < 2; ++i) {
        int r  = wave * 32 + i * 16 + (lane >> 2);
        int cs = (((lane & 3) ^ (r & 3)) << 3);
        pA[i] = z_m + (size_t)min(n0 + r, NN - 1) * FF + cs;
        pB[i] = w1t + (size_t)r * KDIM + cs;
        lA[i] = (u16*)As + (wave * 2 + i) * 512;
        lB[i] = (u16*)Bs + (wave * 2 + i) * 512;
    }

    int aoff[4], boff[4];
    #pragma unroll
    for (int ti = 0; ti < 4; ++ti) {
        int rowa = wr * 64 + ti * 16 + l15;
        aoff[ti] = rowa * BK + (((quad ^ (rowa & 3))) << 3);
        int rowb = wc * 64 + ti * 16 + l15;
        boff[ti] = rowb * BK + (((quad ^ (rowb & 3))) << 3);
    }

    floatx4 acc[4][4] = {};

    for (int k0 = 0; k0 < KDIM; k0 += BK) {
        __syncthreads();
        #pragma unroll
        for (int i = 0; i < 2; ++i) {
            gload_lds16(pA[i] + k0, lA[i]);
            gload_lds16(pB[i] + k0, lB[i]);
        }
        __syncthreads();

        short8 afr[4], bfr[4];
        #pragma unroll
        for (int ti = 0; ti < 4; ++ti)
            afr[ti] = *(const short8*)(&As[aoff[ti]]);
        #pragma unroll
        for (int tj = 0; tj < 4; ++tj)
            bfr[tj] = *(const short8*)(&Bs[boff[tj]]);
        #pragma unroll
        for (int ti = 0; ti < 4; ++ti)
            #pragma unroll
            for (int tj = 0; tj < 4; ++tj)
                acc[ti][tj] = __builtin_amdgcn_mfma_f32_16x16x32_bf16(
                    afr[ti], bfr[tj], acc[ti][tj], 0, 0, 0);
    }

    float b1v[4], w2v[4];
    #pragma unroll
    for (int tj = 0; tj < 4; ++tj) {
        int c = wc * 64 + tj * 16 + l15;
        b1v[tj] = b1[c];
        w2v[tj] = w2[c];
    }
    float local = 0.f;
    #pragma unroll
    for (int ti = 0; ti < 4; ++ti) {
        #pragma unroll
        for (int reg = 0; reg < 4; ++reg) {
            int n = n0 + wr * 64 + ti * 16 + quad * 4 + reg;
            if (n < NN) {
                #pragma unroll
                for (int tj = 0; tj < 4; ++tj)
                    local += tanhf(acc[ti][tj][reg] + b1v[tj]) * w2v[tj];
            }
        }
    }
    #pragma unroll
    for (int s = 1; s < 64; s <<= 1) local += __shfl_xor(local, s);
    if (lane == 0) atomicAdd(&wsum[m], local);
}

// ---------------------------------------------------------------------------
// out[n,:] = sum_m softmax(wsum/NN)[m] * z[m,n,:]  (fp32 out, uint4 lanes)
// ---------------------------------------------------------------------------
__global__ __launch_bounds__(256) void k_combine(
    const u16* __restrict__ z, const float* __restrict__ wsum,
    float* __restrict__ out)
{
    float s0 = wsum[0] / (float)NN, s1 = wsum[1] / (float)NN, s2 = wsum[2] / (float)NN;
    float mx = fmaxf(s0, fmaxf(s1, s2));
    float e0 = expf(s0 - mx), e1 = expf(s1 - mx), e2 = expf(s2 - mx);
    float inv = 1.f / (e0 + e1 + e2);
    float aw[3] = { e0 * inv, e1 * inv, e2 * inv };

    long long idx = (long long)blockIdx.x * 256 + threadIdx.x;
    if (idx >= (long long)NN * 32) return;
    int n = (int)(idx >> 5), c = (int)(idx & 31) * 8;
    float acc[8] = {0.f, 0.f, 0.f, 0.f, 0.f, 0.f, 0.f, 0.f};
    #pragma unroll
    for (int m = 0; m < MM; ++m) {
        uint4 f = *(const uint4*)(z + ((size_t)m * NN + n) * FF + c);
        float a = aw[m];
        acc[0] += a * b2f_lo(f.x); acc[1] += a * b2f_hi(f.x);
        acc[2] += a * b2f_lo(f.y); acc[3] += a * b2f_hi(f.y);
        acc[4] += a * b2f_lo(f.z); acc[5] += a * b2f_hi(f.z);
        acc[6] += a * b2f_lo(f.w); acc[7] += a * b2f_hi(f.w);
    }
    float* op = out + (size_t)n * FF + c;
    *(float4*)op       = make_float4(acc[0], acc[1], acc[2], acc[3]);
    *(float4*)(op + 4) = make_float4(acc[4], acc[5], acc[6], acc[7]);
}

extern "C" void kernel_launch(void* const* d_in, const int* in_sizes, int n_in,
                              void* d_out, int out_size, void* d_ws, size_t ws_size,
                              hipStream_t stream)
{
    const float* hmat = (const float*)d_in[0];
    const int*   src  = (const int*)d_in[1];
    const int*   dst  = (const int*)d_in[2];
    const float* fcw  = (const float*)d_in[3];
    const float* al   = (const float*)d_in[4];
    const float* ar   = (const float*)d_in[5];
    const float* bias = (const float*)d_in[6];
    const float* w1   = (const float*)d_in[7];
    const float* b1   = (const float*)d_in[8];
    const float* w2   = (const float*)d_in[9];
    float* out = (float*)d_out;

    // workspace: ~190 MB (< 220 MB proven safe)
    char* ws = (char*)d_ws;
    size_t off = 0;
    auto alloc = [&](size_t nbytes) {
        void* p = (void*)(ws + off);
        off = (off + nbytes + 255) & ~(size_t)255;
        return p;
    };
    float* el   = (float*)alloc((size_t)MM * NN * HH * 4);      // 4.8 MB
    float* er   = (float*)alloc((size_t)MM * NN * HH * 4);      // 4.8 MB
    float* wsum = (float*)alloc(256);
    int*   cnt  = (int*)alloc((size_t)MM * NN * 4);             // 0.6 MB
    u16*   srt  = (u16*)alloc((size_t)MM * CAP * NN * 2);       // 24 MB (slot-major)
    u16*   fcwt = (u16*)alloc((size_t)MM * KDIM * FF * 2);      // 0.4 MB
    u16*   w1t  = (u16*)alloc((size_t)HID * KDIM * 2);          // 64 KB
    u16*   featb= (u16*)alloc((size_t)MM * NN * FF * 2);        // 76.8 MB
    u16*   z    = (u16*)alloc((size_t)MM * NN * FF * 2);        // 76.8 MB

    hipMemsetAsync(wsum, 0, 256, stream);
    hipMemsetAsync(cnt, 0, (size_t)MM * NN * 4, stream);

    // weight casts (tiny)
    k_prep_w<<<896, 256, 0, stream>>>(fcw, fcwt, w1, w1t);

    // feat GEMM + fused scatter, split by column-half cy (attribution)
    for (int cy = 0; cy < 2; ++cy)
        k_feat_all<<<dim3((NN + 127) / 128, MM), 256, 0, stream>>>(
            hmat, fcwt, al, ar, featb, el, er, src, dst, cnt, srt, cy);

    // aggr: 3 d-range pieces, same cross-m grid (attribution + bubble probe)
    k_aggr_all<<<dim3(2084, MM), 256, 0, stream>>>(cnt, srt, el, er, featb, bias, z, 0);
    k_aggr_all<<<dim3(2084, MM), 256, 0, stream>>>(cnt, srt, el, er, featb, bias, z, 16672);
    k_aggr_all<<<dim3(2082, MM), 256, 0, stream>>>(cnt, srt, el, er, featb, bias, z, 33344);

    k_sem_all<<<dim3((NN + 127) / 128, MM), 256, 0, stream>>>(z, w1t, b1, w2, wsum);
    k_combine<<<(int)(((size_t)NN * 32 + 255) / 256), 256, 0, stream>>>(z, wsum, out);
}

// Round 8
// 553.834 us; speedup vs baseline: 1.1012x; 1.1012x over previous
//
#include <hip/hip_runtime.h>
#include <math.h>

#define NN   50000
#define EE   800000
#define MM   3
#define KDIM 256      // IN_DIM
#define FF   256      // H*D
#define HH   8
#define DD   32
#define HID  128
#define SLOPE 0.2f
#define BK   32       // k-slice per MFMA stage
#define CAP  64       // CSR capacity/node. Poisson(16): P(deg>=64)*150K ~ 3e-13
                      // (fixed-seed max deg ~48). 80->64 cuts aggr LDS 23->18.4KB
                      // -> 8 blocks/CU (was 6) for gather concurrency.

typedef unsigned short u16;
typedef unsigned int   u32;
typedef __attribute__((ext_vector_type(8))) short short8;   // 8 bf16 = 4 VGPRs
typedef __attribute__((ext_vector_type(4))) float floatx4;  // MFMA acc

__device__ __forceinline__ float eluf(float x) { return x > 0.f ? x : expm1f(x); }

__device__ __forceinline__ float b2f_lo(u32 u) {
    union { u32 i; float f; } v; v.i = u << 16; return v.f;
}
__device__ __forceinline__ float b2f_hi(u32 u) {
    union { u32 i; float f; } v; v.i = u & 0xffff0000u; return v.f;
}
__device__ __forceinline__ u16 f2b(float f) {
    union { float f; u32 i; } v; v.f = f;
    u32 lsb = (v.i >> 16) & 1u;
    v.i += 0x7fffu + lsb;
    return (u16)(v.i >> 16);
}
__device__ __forceinline__ u32 pack2(float lo, float hi) {
    return (u32)f2b(lo) | ((u32)f2b(hi) << 16);
}

// async global->LDS, 16B per lane; LDS dest = wave-uniform base + lane*16
__device__ __forceinline__ void gload_lds16(const u16* g, u16* l) {
    __builtin_amdgcn_global_load_lds(
        (const __attribute__((address_space(1))) unsigned int*)(const void*)g,
        (__attribute__((address_space(3))) unsigned int*)(void*)l,
        16, 0, 0);
}

// ---------------------------------------------------------------------------
// k_prep_w: weight casts + cnt/wsum zeroing (memsets folded in; 7->5
// dispatches total).  Blocks: [0,768) cast_w, [768,896) cast_w1,
// [896,1043) cnt-zero (uint4), 1043 wsum-zero.
// ---------------------------------------------------------------------------
__global__ __launch_bounds__(256) void k_prep_w(
    const float* __restrict__ fcw,  u16* __restrict__ fcwt,
    const float* __restrict__ w1,   u16* __restrict__ w1t,
    int* __restrict__ cnt, float* __restrict__ wsum)
{
    const int bid = blockIdx.x;
    const int t = threadIdx.x;
    if (bid < 768) {
        int k = bid & 255, me = bid >> 8, n = t;
        float v = fcw[((size_t)me * KDIM + k) * FF + n];
        fcwt[((size_t)me * FF + n) * KDIM + k] = f2b(v);
    } else if (bid < 896) {
        int idx = (bid - 768) * 256 + t;   // 32768 elems
        int k = idx >> 7, n = idx & 127;
        w1t[(size_t)n * KDIM + k] = f2b(w1[(size_t)k * HID + n]);
    } else if (bid < 1043) {
        int idx = (bid - 896) * 256 + t;   // 37500 uint4 = MM*NN ints
        if (idx < (MM * NN) / 4)
            ((uint4*)cnt)[idx] = make_uint4(0u, 0u, 0u, 0u);
    } else {
        if (t < 16) ((uint4*)wsum)[t] = make_uint4(0u, 0u, 0u, 0u);
    }
}

// ---------------------------------------------------------------------------
// feat[m] = h @ fcw[m] via MFMA bf16 + FUSED full edge scatter prologue
// (R3/R5 structure, best measured: one 2346-block dispatch keeps max atomics
// in flight — splitting regresses, R6).  A staged from hmat f32 + in-kernel
// f2b; B via global_load_lds w16; XOR-(row&3) slot swizzle both-sides.
// ---------------------------------------------------------------------------
__global__ __launch_bounds__(256) void k_feat_all(
    const float* __restrict__ hmat,    // [N,256] f32
    const u16*   __restrict__ fcwt,    // [M][256(n)][256(k)] bf16
    const float* __restrict__ al,      // [M,H,D]
    const float* __restrict__ ar,      // [M,H,D]
    u16*   __restrict__ featb,         // [M,N,256] bf16
    float* __restrict__ el,            // [M,N,H]
    float* __restrict__ er,            // [M,N,H]
    const int* __restrict__ src,       // [M*E]
    const int* __restrict__ dst,       // [M*E]
    int* __restrict__ cnt,             // [M,NN]
    u16* __restrict__ srt)             // [M,CAP,NN] slot-major
{
    __shared__ u16 As[128 * BK];   // 8 KB, linear+swizzled
    __shared__ u16 Bs[128 * BK];   // 8 KB

    const int t = threadIdx.x;

    // --- fused scatter: 4 consecutive edges per thread (EE%4==0) ---
    {
        int bid = blockIdx.x + 391 * (blockIdx.y + 2 * blockIdx.z);
        long long base = ((long long)bid * 256 + t) * 4;
        if (base < (long long)MM * EE) {
            int4 d4 = *(const int4*)(dst + base);
            int4 s4 = *(const int4*)(src + base);
            int me = (int)(base / EE);
            int* cnt_m = cnt + (size_t)me * NN;
            u16* srt_m = srt + (size_t)me * CAP * NN;
            int dd4[4] = { d4.x, d4.y, d4.z, d4.w };
            int ss4[4] = { s4.x, s4.y, s4.z, s4.w };
            #pragma unroll
            for (int j = 0; j < 4; ++j) {
                int slot = atomicAdd(&cnt_m[dd4[j]], 1);
                if (slot < CAP) srt_m[(size_t)slot * NN + dd4[j]] = (u16)ss4[j];
            }
        }
    }

    const int n0 = blockIdx.x * 128;
    const int cy = blockIdx.y;          // column half: heads cy*4..cy*4+3
    const int m  = blockIdx.z;
    const int c_base = cy * 128;
    const int wave = t >> 6, lane = t & 63;
    const int wr = wave >> 1, wc = wave & 1;
    const int quad = lane >> 4, l15 = lane & 15;

    const u16* fcwt_m = fcwt + (size_t)m * FF * KDIM;
    const float* al_m = al + (size_t)m * HH * DD;
    const float* ar_m = ar + (size_t)m * HH * DD;

    const float* pAf[2]; const u16* pB[2]; u16* lA[2]; u16* lB[2];
    #pragma unroll
    for (int i = 0; i < 2; ++i) {
        int r  = wave * 32 + i * 16 + (lane >> 2);
        int cs = (((lane & 3) ^ (r & 3)) << 3);
        pAf[i] = hmat + (size_t)min(n0 + r, NN - 1) * KDIM + cs;  // f32 source
        pB[i]  = fcwt_m + (size_t)(c_base + r) * KDIM + cs;
        lA[i] = (u16*)As + (wave * 2 + i) * 512 + lane * 8;       // per-lane 16B
        lB[i] = (u16*)Bs + (wave * 2 + i) * 512;                  // wave-uniform
    }

    int aoff[4], boff[4];
    #pragma unroll
    for (int ti = 0; ti < 4; ++ti) {
        int rowa = wr * 64 + ti * 16 + l15;
        aoff[ti] = rowa * BK + (((quad ^ (rowa & 3))) << 3);
        int rowb = wc * 64 + ti * 16 + l15;
        boff[ti] = rowb * BK + (((quad ^ (rowb & 3))) << 3);
    }

    floatx4 acc[4][4] = {};

    for (int k0 = 0; k0 < KDIM; k0 += BK) {
        __syncthreads();
        #pragma unroll
        for (int i = 0; i < 2; ++i)
            gload_lds16(pB[i] + k0, lB[i]);
        #pragma unroll
        for (int i = 0; i < 2; ++i) {
            float4 v0 = *(const float4*)(pAf[i] + k0);
            float4 v1 = *(const float4*)(pAf[i] + k0 + 4);
            uint4 u;
            u.x = pack2(v0.x, v0.y); u.y = pack2(v0.z, v0.w);
            u.z = pack2(v1.x, v1.y); u.w = pack2(v1.z, v1.w);
            *(uint4*)(lA[i]) = u;
        }
        __syncthreads();

        short8 afr[4], bfr[4];
        #pragma unroll
        for (int ti = 0; ti < 4; ++ti)
            afr[ti] = *(const short8*)(&As[aoff[ti]]);
        #pragma unroll
        for (int tj = 0; tj < 4; ++tj)
            bfr[tj] = *(const short8*)(&Bs[boff[tj]]);
        #pragma unroll
        for (int ti = 0; ti < 4; ++ti)
            #pragma unroll
            for (int tj = 0; tj < 4; ++tj)
                acc[ti][tj] = __builtin_amdgcn_mfma_f32_16x16x32_bf16(
                    afr[ti], bfr[tj], acc[ti][tj], 0, 0, 0);
    }

    float alv[4], arv[4];
    #pragma unroll
    for (int tj = 0; tj < 4; ++tj) {
        int h = cy * 4 + wc * 2 + (tj >> 1);
        int dcol = (tj & 1) * 16 + l15;
        alv[tj] = al_m[h * DD + dcol];
        arv[tj] = ar_m[h * DD + dcol];
    }
    const int h0 = cy * 4 + wc * 2, h1 = h0 + 1;

    #pragma unroll
    for (int ti = 0; ti < 4; ++ti) {
        #pragma unroll
        for (int reg = 0; reg < 4; ++reg) {
            int n = n0 + wr * 64 + ti * 16 + quad * 4 + reg;
            bool ok = n < NN;
            if (ok) {
                #pragma unroll
                for (int tj = 0; tj < 4; ++tj) {
                    int c = c_base + wc * 64 + tj * 16 + l15;
                    featb[((size_t)m * NN + n) * FF + c] = f2b(acc[ti][tj][reg]);
                }
            }
            float pl0 = acc[ti][0][reg] * alv[0] + acc[ti][1][reg] * alv[1];
            float pl1 = acc[ti][2][reg] * alv[2] + acc[ti][3][reg] * alv[3];
            float pr0 = acc[ti][0][reg] * arv[0] + acc[ti][1][reg] * arv[1];
            float pr1 = acc[ti][2][reg] * arv[2] + acc[ti][3][reg] * arv[3];
            #pragma unroll
            for (int s = 1; s < 16; s <<= 1) {
                pl0 += __shfl_xor(pl0, s); pl1 += __shfl_xor(pl1, s);
                pr0 += __shfl_xor(pr0, s); pr1 += __shfl_xor(pr1, s);
            }
            if (l15 == 0 && ok) {
                el[((size_t)m * NN + n) * HH + h0] = pl0;
                el[((size_t)m * NN + n) * HH + h1] = pl1;
                er[((size_t)m * NN + n) * HH + h0] = pr0;
                er[((size_t)m * NN + n) * HH + h1] = pr1;
            }
        }
    }
}

// ---------------------------------------------------------------------------
// Aggregation — single cross-m dispatch (measured best).  CAP=64 shrinks LDS
// 23->18.4KB -> 8 blocks/CU (was 6): more waves = more outstanding gathers.
// ---------------------------------------------------------------------------
__global__ __launch_bounds__(256) void k_aggr_all(
    const int* __restrict__ cnt,        // [M,NN]
    const u16* __restrict__ srt,        // [M,CAP,NN] slot-major
    const float* __restrict__ el,       // [M,NN,8]
    const float* __restrict__ er,       // [M,NN,8]
    const u16* __restrict__ featb,      // [M,NN,256] bf16
    const float* __restrict__ bias,     // [M,256]
    u16* __restrict__ z)                // [M,NN,256] bf16
{
    __shared__ float alpha_s[4][2][CAP][HH];  // 16 KB
    __shared__ int   srcoff[4][2][CAP];       // 2 KB (s*FF)

    const int m = blockIdx.y;
    const int wave = threadIdx.x >> 6, lane = threadIdx.x & 63;
    const int half = lane >> 5, L = lane & 31;
    const int d = blockIdx.x * 8 + wave * 2 + half;

    const int deg = min(cnt[(size_t)m * NN + d], CAP);
    const float* el_m = el + (size_t)m * NN * HH;
    const u16* feat_m = featb + (size_t)m * NN * FF;

    #pragma unroll
    for (int i = 0; i < 2; ++i) {
        int slot = L + i * 32;
        if (slot < deg)
            srcoff[wave][half][slot] =
                (int)srt[(size_t)(m * CAP + slot) * NN + d] * FF;
    }

    // phase A: exp + esum. lane = edge (L>>3) x head (L&7), unroll x2
    const int hA = L & 7;
    const float er_d = er[((size_t)m * NN + d) * HH + hA];
    float esum_r = 0.f;
    const int nIter = (deg + 3) >> 2;
    int i = 0;
    for (; i + 2 <= nIter; i += 2) {
        int j0 = i * 4 + (L >> 3);
        int j1 = j0 + 4;
        bool v0 = j0 < deg, v1 = j1 < deg;
        int so0 = v0 ? srcoff[wave][half][j0] : 0;
        int so1 = v1 ? srcoff[wave][half][j1] : 0;
        float x0 = el_m[(size_t)(so0 >> 5) + hA] + er_d;
        float x1 = el_m[(size_t)(so1 >> 5) + hA] + er_d;
        x0 = x0 >= 0.f ? x0 : SLOPE * x0;  x0 = fminf(x0, 60.f);
        x1 = x1 >= 0.f ? x1 : SLOPE * x1;  x1 = fminf(x1, 60.f);
        float e0 = v0 ? expf(x0) : 0.f;
        float e1 = v1 ? expf(x1) : 0.f;
        if (v0) alpha_s[wave][half][j0][hA] = e0;
        if (v1) alpha_s[wave][half][j1][hA] = e1;
        float g = e0 + e1;
        g += __shfl_xor(g, 8); g += __shfl_xor(g, 16);
        esum_r += g;
    }
    for (; i < nIter; ++i) {
        int j = i * 4 + (L >> 3);
        float e = 0.f;
        if (j < deg) {
            int so = srcoff[wave][half][j];
            float x = el_m[(size_t)(so >> 5) + hA] + er_d;
            x = x >= 0.f ? x : SLOPE * x;
            x = fminf(x, 60.f);
            e = expf(x);
            alpha_s[wave][half][j][hA] = e;
        }
        float g = e;
        g += __shfl_xor(g, 8); g += __shfl_xor(g, 16);
        esum_r += g;
    }
    float inv_r = 1.f / fmaxf(esum_r, 1e-38f);

    // phase B: lane covers channels L*8..L*8+7 of dst d; head = L>>2
    const float inv_g = __shfl(inv_r, (lane & 32) | (L >> 2));
    const int hB = L >> 2;
    const u16* frow = feat_m + L * 8;
    float acc[8] = {0.f, 0.f, 0.f, 0.f, 0.f, 0.f, 0.f, 0.f};

#define ACC8(f, a)                                                  \
    acc[0] += (a) * b2f_lo((f).x); acc[1] += (a) * b2f_hi((f).x);   \
    acc[2] += (a) * b2f_lo((f).y); acc[3] += (a) * b2f_hi((f).y);   \
    acc[4] += (a) * b2f_lo((f).z); acc[5] += (a) * b2f_hi((f).z);   \
    acc[6] += (a) * b2f_lo((f).w); acc[7] += (a) * b2f_hi((f).w);

    int j = 0;
    for (; j + 4 <= deg; j += 4) {
        int so0 = srcoff[wave][half][j + 0];
        int so1 = srcoff[wave][half][j + 1];
        int so2 = srcoff[wave][half][j + 2];
        int so3 = srcoff[wave][half][j + 3];
        float a0 = alpha_s[wave][half][j + 0][hB];
        float a1 = alpha_s[wave][half][j + 1][hB];
        float a2 = alpha_s[wave][half][j + 2][hB];
        float a3 = alpha_s[wave][half][j + 3][hB];
        uint4 f0 = *(const uint4*)(frow + so0);
        uint4 f1 = *(const uint4*)(frow + so1);
        uint4 f2 = *(const uint4*)(frow + so2);
        uint4 f3 = *(const uint4*)(frow + so3);
        ACC8(f0, a0); ACC8(f1, a1); ACC8(f2, a2); ACC8(f3, a3);
    }
    for (; j < deg; ++j) {
        int so = srcoff[wave][half][j];
        float a = alpha_s[wave][half][j][hB];
        uint4 f = *(const uint4*)(frow + so);
        ACC8(f, a);
    }
#undef ACC8

    #pragma unroll
    for (int k = 0; k < 8; ++k) acc[k] *= inv_g;

    const float4 b0 = *(const float4*)(bias + (size_t)m * FF + L * 8);
    const float4 b1 = *(const float4*)(bias + (size_t)m * FF + L * 8 + 4);
    uint4 o;
    o.x = pack2(eluf(acc[0] + b0.x), eluf(acc[1] + b0.y));
    o.y = pack2(eluf(acc[2] + b0.z), eluf(acc[3] + b0.w));
    o.z = pack2(eluf(acc[4] + b1.x), eluf(acc[5] + b1.y));
    o.w = pack2(eluf(acc[6] + b1.z), eluf(acc[7] + b1.w));
    *(uint4*)(z + ((size_t)m * NN + d) * FF + L * 8) = o;
}

// ---------------------------------------------------------------------------
// wsum[m] = sum_n tanh(z[m] @ w1 + b1) @ w2  via MFMA (single dispatch).
// ---------------------------------------------------------------------------
__global__ __launch_bounds__(256) void k_sem_all(
    const u16* __restrict__ z,        // [M,NN,256] bf16
    const u16* __restrict__ w1t,      // [128(n)][256(k)] bf16
    const float* __restrict__ b1,     // [128]
    const float* __restrict__ w2,     // [128]
    float* __restrict__ wsum)         // [M]
{
    __shared__ u16 As[128 * BK];
    __shared__ u16 Bs[128 * BK];

    const int n0 = blockIdx.x * 128;
    const int m  = blockIdx.y;
    const int t = threadIdx.x;
    const int wave = t >> 6, lane = t & 63;
    const int wr = wave >> 1, wc = wave & 1;
    const int quad = lane >> 4, l15 = lane & 15;

    const u16* z_m = z + (size_t)m * NN * FF;

    const u16* pA[2]; const u16* pB[2]; u16* lA[2]; u16* lB[2];
    #pragma unroll
    for (int i = 0; i < 2; ++i) {
        int r  = wave * 32 + i * 16 + (lane >> 2);
        int cs = (((lane & 3) ^ (r & 3)) << 3);
        pA[i] = z_m + (size_t)min(n0 + r, NN - 1) * FF + cs;
        pB[i] = w1t + (size_t)r * KDIM + cs;
        lA[i] = (u16*)As + (wave * 2 + i) * 512;
        lB[i] = (u16*)Bs + (wave * 2 + i) * 512;
    }

    int aoff[4], boff[4];
    #pragma unroll
    for (int ti = 0; ti < 4; ++ti) {
        int rowa = wr * 64 + ti * 16 + l15;
        aoff[ti] = rowa * BK + (((quad ^ (rowa & 3))) << 3);
        int rowb = wc * 64 + ti * 16 + l15;
        boff[ti] = rowb * BK + (((quad ^ (rowb & 3))) << 3);
    }

    floatx4 acc[4][4] = {};

    for (int k0 = 0; k0 < KDIM; k0 += BK) {
        __syncthreads();
        #pragma unroll
        for (int i = 0; i < 2; ++i) {
            gload_lds16(pA[i] + k0, lA[i]);
            gload_lds16(pB[i] + k0, lB[i]);
        }
        __syncthreads();

        short8 afr[4], bfr[4];
        #pragma unroll
        for (int ti = 0; ti < 4; ++ti)
            afr[ti] = *(const short8*)(&As[aoff[ti]]);
        #pragma unroll
        for (int tj = 0; tj < 4; ++tj)
            bfr[tj] = *(const short8*)(&Bs[boff[tj]]);
        #pragma unroll
        for (int ti = 0; ti < 4; ++ti)
            #pragma unroll
            for (int tj = 0; tj < 4; ++tj)
                acc[ti][tj] = __builtin_amdgcn_mfma_f32_16x16x32_bf16(
                    afr[ti], bfr[tj], acc[ti][tj], 0, 0, 0);
    }

    float b1v[4], w2v[4];
    #pragma unroll
    for (int tj = 0; tj < 4; ++tj) {
        int c = wc * 64 + tj * 16 + l15;
        b1v[tj] = b1[c];
        w2v[tj] = w2[c];
    }
    float local = 0.f;
    #pragma unroll
    for (int ti = 0; ti < 4; ++ti) {
        #pragma unroll
        for (int reg = 0; reg < 4; ++reg) {
            int n = n0 + wr * 64 + ti * 16 + quad * 4 + reg;
            if (n < NN) {
                #pragma unroll
                for (int tj = 0; tj < 4; ++tj)
                    local += tanhf(acc[ti][tj][reg] + b1v[tj]) * w2v[tj];
            }
        }
    }
    #pragma unroll
    for (int s = 1; s < 64; s <<= 1) local += __shfl_xor(local, s);
    if (lane == 0) atomicAdd(&wsum[m], local);
}

// ---------------------------------------------------------------------------
// out[n,:] = sum_m softmax(wsum/NN)[m] * z[m,n,:]  (fp32 out, uint4 lanes)
// ---------------------------------------------------------------------------
__global__ __launch_bounds__(256) void k_combine(
    const u16* __restrict__ z, const float* __restrict__ wsum,
    float* __restrict__ out)
{
    float s0 = wsum[0] / (float)NN, s1 = wsum[1] / (float)NN, s2 = wsum[2] / (float)NN;
    float mx = fmaxf(s0, fmaxf(s1, s2));
    float e0 = expf(s0 - mx), e1 = expf(s1 - mx), e2 = expf(s2 - mx);
    float inv = 1.f / (e0 + e1 + e2);
    float aw[3] = { e0 * inv, e1 * inv, e2 * inv };

    long long idx = (long long)blockIdx.x * 256 + threadIdx.x;
    if (idx >= (long long)NN * 32) return;
    int n = (int)(idx >> 5), c = (int)(idx & 31) * 8;
    float acc[8] = {0.f, 0.f, 0.f, 0.f, 0.f, 0.f, 0.f, 0.f};
    #pragma unroll
    for (int m = 0; m < MM; ++m) {
        uint4 f = *(const uint4*)(z + ((size_t)m * NN + n) * FF + c);
        float a = aw[m];
        acc[0] += a * b2f_lo(f.x); acc[1] += a * b2f_hi(f.x);
        acc[2] += a * b2f_lo(f.y); acc[3] += a * b2f_hi(f.y);
        acc[4] += a * b2f_lo(f.z); acc[5] += a * b2f_hi(f.z);
        acc[6] += a * b2f_lo(f.w); acc[7] += a * b2f_hi(f.w);
    }
    float* op = out + (size_t)n * FF + c;
    *(float4*)op       = make_float4(acc[0], acc[1], acc[2], acc[3]);
    *(float4*)(op + 4) = make_float4(acc[4], acc[5], acc[6], acc[7]);
}

extern "C" void kernel_launch(void* const* d_in, const int* in_sizes, int n_in,
                              void* d_out, int out_size, void* d_ws, size_t ws_size,
                              hipStream_t stream)
{
    const float* hmat = (const float*)d_in[0];
    const int*   src  = (const int*)d_in[1];
    const int*   dst  = (const int*)d_in[2];
    const float* fcw  = (const float*)d_in[3];
    const float* al   = (const float*)d_in[4];
    const float* ar   = (const float*)d_in[5];
    const float* bias = (const float*)d_in[6];
    const float* w1   = (const float*)d_in[7];
    const float* b1   = (const float*)d_in[8];
    const float* w2   = (const float*)d_in[9];
    float* out = (float*)d_out;

    // workspace: ~185 MB (< 220 MB proven safe)
    char* ws = (char*)d_ws;
    size_t off = 0;
    auto alloc = [&](size_t nbytes) {
        void* p = (void*)(ws + off);
        off = (off + nbytes + 255) & ~(size_t)255;
        return p;
    };
    float* el   = (float*)alloc((size_t)MM * NN * HH * 4);      // 4.8 MB
    float* er   = (float*)alloc((size_t)MM * NN * HH * 4);      // 4.8 MB
    float* wsum = (float*)alloc(256);
    int*   cnt  = (int*)alloc((size_t)MM * NN * 4);             // 0.6 MB
    u16*   srt  = (u16*)alloc((size_t)MM * CAP * NN * 2);       // 19.2 MB (slot-major)
    u16*   fcwt = (u16*)alloc((size_t)MM * KDIM * FF * 2);      // 0.4 MB
    u16*   w1t  = (u16*)alloc((size_t)HID * KDIM * 2);          // 64 KB
    u16*   featb= (u16*)alloc((size_t)MM * NN * FF * 2);        // 76.8 MB
    u16*   z    = (u16*)alloc((size_t)MM * NN * FF * 2);        // 76.8 MB

    // weight casts + cnt/wsum zeroing (memsets folded in)
    k_prep_w<<<1044, 256, 0, stream>>>(fcw, fcwt, w1, w1t, cnt, wsum);

    // feat GEMM (A from hmat f32, converted in-kernel) + full fused scatter
    k_feat_all<<<dim3((NN + 127) / 128, 2, MM), 256, 0, stream>>>(
        hmat, fcwt, al, ar, featb, el, er, src, dst, cnt, srt);

    k_aggr_all<<<dim3(NN / 8, MM), 256, 0, stream>>>(
        cnt, srt, el, er, featb, bias, z);
    k_sem_all<<<dim3((NN + 127) / 128, MM), 256, 0, stream>>>(z, w1t, b1, w2, wsum);
    k_combine<<<(int)(((size_t)NN * 32 + 255) / 256), 256, 0, stream>>>(z, wsum, out);
}